// Round 13
// baseline (642.945 us; speedup 1.0000x reference)
//
#include <hip/hip_runtime.h>
#include <hip/hip_bf16.h>
#include <math.h>

// Problem constants
#define B_   4
#define L_   2048
#define DM_  1024
#define DS_  16
#define DI_  2048          // EXP * DM
#define DR_  64            // (DM+15)//16
#define MROWS (B_ * L_)    // 8192

typedef __attribute__((ext_vector_type(8))) short bf16x8;
typedef __attribute__((ext_vector_type(4))) float f32x4;

__device__ inline float softplusf(float x) {
    return (x > 20.f) ? x : log1pf(expf(x));
}

// ---------------- split fp32 -> bf16 hi/lo (x ~= hi + lo, rel err ~2^-17) ----------------
__device__ inline void splitbf(float x, short& h, short& l) {
    unsigned u = __builtin_bit_cast(unsigned, x);
    unsigned r = (u + 0x7FFFu + ((u >> 16) & 1u)) & 0xFFFF0000u;
    h = (short)(r >> 16);
    float lf = x - __builtin_bit_cast(float, r);
    unsigned u2 = __builtin_bit_cast(unsigned, lf);
    unsigned r2 = u2 + 0x7FFFu + ((u2 >> 16) & 1u);
    l = (short)(r2 >> 16);
}

__device__ inline float bfh2f(unsigned hs) {
    return __builtin_bit_cast(float, hs << 16);
}

// X:[R][Kin] f32 -> H,L:[Ralloc][Kin] bf16, rows >= R zeroed
__global__ __launch_bounds__(256) void pack_hl(
    const float* __restrict__ X, short* __restrict__ H, short* __restrict__ L,
    int R, int Ralloc, int Kin)
{
    int idx = blockIdx.x * 256 + threadIdx.x;       // over Ralloc*Kin/4
    int kq = Kin >> 2;
    if (idx >= Ralloc * kq) return;
    int k4 = (idx % kq) * 4, r = idx / kq;
    short4 hi = make_short4(0,0,0,0), lo = make_short4(0,0,0,0);
    if (r < R) {
        float4 v = *(const float4*)&X[(size_t)r * Kin + k4];
        splitbf(v.x, hi.x, lo.x); splitbf(v.y, hi.y, lo.y);
        splitbf(v.z, hi.z, lo.z); splitbf(v.w, hi.w, lo.w);
    }
    size_t base = (size_t)r * Kin + k4;
    *(short4*)&H[base] = hi;
    *(short4*)&L[base] = lo;
}

__device__ inline void gload_lds16(const void* g, void* s) {
    __builtin_amdgcn_global_load_lds(
        (const __attribute__((address_space(1))) void*)g,
        (__attribute__((address_space(3))) void*)s, 16, 0, 0);
}

// ================= Pipelined MFMA split-bf16 GEMM (in_proj / out_proj) =================
// C[MxN] = A*B^T via HH+HL+LH, BM=256 BN=128 BK=32, 8 waves 4M x 2N (wave tile 64x64).
// Triple-buffered LDS, 2-ahead prefetch, counted vmcnt(6). Swizzle (rule #21): linear LDS
// dest + pre-swizzled GLOBAL source + swizzled read -> bank conflicts = 0 (measured R11).
// Register double-buffered frags; sched_barrier(0) between next-tile ds_reads and the
// current-tile MFMA cluster pins issue order so the compiler cannot sink the reads to
// their use point (R12: VGPR=116 proved it sank them; per-tile = MFMA+LDS serialized).
// LDS buf layout (shorts): Ah[0,8192) Al[8192,16384) Bh[16384,20480) Bl[20480,24576).
__device__ inline void stage_tile(
    const short* __restrict__ aH, const short* __restrict__ aL,
    const short* __restrict__ bH, const short* __restrict__ bL,
    short* buf, int m0, int n0, int k0, int lda, int tid)
{
    int c0 = tid, c1 = tid + 512;
    int r0 = c0 >> 2, r1 = c1 >> 2;
    int p0 = (((c0 & 3) ^ ((r0 >> 1) & 3)) << 3);   // swizzled source chunk offset
    int p1 = (((c1 & 3) ^ ((r1 >> 1) & 3)) << 3);
    int ub0 = (tid & ~63) * 8;                      // wave-uniform LDS short-offset
    int ub1 = ((tid & ~63) + 512) * 8;
    gload_lds16(&aH[(size_t)(m0 + r0) * lda + k0 + p0], buf + ub0);
    gload_lds16(&aH[(size_t)(m0 + r1) * lda + k0 + p1], buf + ub1);
    gload_lds16(&aL[(size_t)(m0 + r0) * lda + k0 + p0], buf + 8192 + ub0);
    gload_lds16(&aL[(size_t)(m0 + r1) * lda + k0 + p1], buf + 8192 + ub1);
    gload_lds16(&bH[(size_t)(n0 + r0) * lda + k0 + p0], buf + 16384 + ub0);
    gload_lds16(&bL[(size_t)(n0 + r0) * lda + k0 + p0], buf + 20480 + ub0);
}

__device__ __forceinline__ void read_frags(
    const short* buf, int wm, int wn, int lr, int hk,
    bf16x8 (&Ah)[4], bf16x8 (&Al)[4], bf16x8 (&Bh)[4], bf16x8 (&Bl)[4])
{
    #pragma unroll
    for (int ni = 0; ni < 4; ++ni) {
        int row = wn * 64 + ni * 16 + lr;
        int off = 16384 + row * 32 + (hk ^ ((row >> 1) & 3)) * 8;
        Bh[ni] = *(const bf16x8*)&buf[off];
        Bl[ni] = *(const bf16x8*)&buf[off + 4096];
    }
    #pragma unroll
    for (int mi = 0; mi < 4; ++mi) {
        int row = wm * 64 + mi * 16 + lr;
        int off = row * 32 + (hk ^ ((row >> 1) & 3)) * 8;
        Ah[mi] = *(const bf16x8*)&buf[off];
        Al[mi] = *(const bf16x8*)&buf[off + 8192];
    }
}

__device__ __forceinline__ void tile_body(
    int t, int NT, short* lds,
    const short* __restrict__ aH, const short* __restrict__ aL,
    const short* __restrict__ bH, const short* __restrict__ bL,
    int m0, int n0, int lda, int tid, int wm, int wn, int lr, int hk,
    bf16x8 (&CAh)[4], bf16x8 (&CAl)[4], bf16x8 (&CBh)[4], bf16x8 (&CBl)[4],
    bf16x8 (&NAh)[4], bf16x8 (&NAl)[4], bf16x8 (&NBh)[4], bf16x8 (&NBl)[4],
    f32x4 (&acc)[4][4])
{
    // 1) stage tile t+2 into buf[(t+2)%3] (== buf[(t-1)%3], last read in tile t-2)
    if (t + 2 < NT)
        stage_tile(aH, aL, bH, bL, &lds[((t + 2) % 3) * 24576],
                   m0, n0, (t + 2) * 32, lda, tid);
    // 2) boundary: drain t+1's stage loads (leave t+2's 6 in flight); barrier
    if (t + 1 < NT) {
        if (t + 2 < NT) asm volatile("s_waitcnt vmcnt(6)\ns_barrier" ::: "memory");
        else            asm volatile("s_waitcnt vmcnt(0)\ns_barrier" ::: "memory");
        // 3) ds_read tile t+1 frags into the NEXT register bank
        read_frags(&lds[((t + 1) % 3) * 24576], wm, wn, lr, hk, NAh, NAl, NBh, NBl);
    }
    // 3b) PIN: reads must be ISSUED before the MFMA cluster; they complete under it.
    __builtin_amdgcn_sched_barrier(0);
    // 4) MFMA on CURRENT bank (no dep on the reads just issued)
    __builtin_amdgcn_s_setprio(1);
    #pragma unroll
    for (int mi = 0; mi < 4; ++mi)
        #pragma unroll
        for (int ni = 0; ni < 4; ++ni) {
            acc[mi][ni] = __builtin_amdgcn_mfma_f32_16x16x32_bf16(CAh[mi], CBh[ni], acc[mi][ni], 0, 0, 0);
            acc[mi][ni] = __builtin_amdgcn_mfma_f32_16x16x32_bf16(CAh[mi], CBl[ni], acc[mi][ni], 0, 0, 0);
            acc[mi][ni] = __builtin_amdgcn_mfma_f32_16x16x32_bf16(CAl[mi], CBh[ni], acc[mi][ni], 0, 0, 0);
        }
    __builtin_amdgcn_s_setprio(0);
}

__global__ __launch_bounds__(512, 2) void gemm_pipe(
    const short* __restrict__ aH, const short* __restrict__ aL,
    const short* __restrict__ bH, const short* __restrict__ bL,
    float* __restrict__ C, int nblocks, int lda, int NT, int ldc)
{
    __shared__ short lds[3 * 24576];
    const int tid = threadIdx.x;
    const int l = tid & 63;
    const int w = tid >> 6;
    const int wm = w & 3;            // 0..3 (M quarter: 64 rows)
    const int wn = w >> 2;           // 0..1 (N half: 64 cols)
    const int lr = l & 15, hk = l >> 4;

    int nwg = gridDim.x;
    int bid = blockIdx.x;
    if ((nwg & 7) == 0) { int cpx = nwg >> 3; bid = (bid & 7) * cpx + (bid >> 3); }
    const int n0 = (bid % nblocks) * 128;
    const int m0 = (bid / nblocks) * 256;

    f32x4 acc[4][4];
    #pragma unroll
    for (int mi = 0; mi < 4; ++mi)
        #pragma unroll
        for (int ni = 0; ni < 4; ++ni) acc[mi][ni] = (f32x4){0.f, 0.f, 0.f, 0.f};

    bf16x8 A0h[4], A0l[4], B0h[4], B0l[4];   // register bank 0
    bf16x8 A1h[4], A1l[4], B1h[4], B1l[4];   // register bank 1

    // prologue: stage tiles 0,1; wait t0 (all waves); read t0 frags -> bank 0
    stage_tile(aH, aL, bH, bL, &lds[0],     m0, n0, 0,  lda, tid);
    stage_tile(aH, aL, bH, bL, &lds[24576], m0, n0, 32, lda, tid);
    asm volatile("s_waitcnt vmcnt(6)\ns_barrier" ::: "memory");
    read_frags(&lds[0], wm, wn, lr, hk, A0h, A0l, B0h, B0l);

    // NT is even (32 or 64): 2x-unrolled loop with named banks (rule #20)
    for (int t = 0; t < NT; t += 2) {
        tile_body(t,     NT, lds, aH, aL, bH, bL, m0, n0, lda, tid, wm, wn, lr, hk,
                  A0h, A0l, B0h, B0l, A1h, A1l, B1h, B1l, acc);
        tile_body(t + 1, NT, lds, aH, aL, bH, bL, m0, n0, lda, tid, wm, wn, lr, hk,
                  A1h, A1l, B1h, B1l, A0h, A0l, B0h, B0l, acc);
    }

    #pragma unroll
    for (int mi = 0; mi < 4; ++mi)
        #pragma unroll
        for (int ni = 0; ni < 4; ++ni) {
            int col = n0 + wn * 64 + ni * 16 + lr;
            int rowb = m0 + wm * 64 + mi * 16 + hk * 4;
            #pragma unroll
            for (int j = 0; j < 4; ++j)
                C[(size_t)(rowb + j) * ldc + col] = acc[mi][ni][j];
        }
}

// ================= old fused GEMM (kept for x_proj split-K and dt), swizzled =========
template<int EPI>
__global__ __launch_bounds__(256) void gemm3(
    const short* __restrict__ aH, const short* __restrict__ aL,
    const short* __restrict__ bH, const short* __restrict__ bL,
    const float* __restrict__ bias, float* __restrict__ C,
    int mblocks, int lda, int kLen, int ldc, int M)
{
    __shared__ short AsH[128 * 32];
    __shared__ short AsL[128 * 32];
    __shared__ short BsH[128 * 32];
    __shared__ short BsL[128 * 32];

    const int tid = threadIdx.x;
    const int l  = tid & 63;
    const int wr = (tid >> 6) >> 1, wc = (tid >> 6) & 1;
    const int lr = l & 15, lk = l >> 4;

    int nwg = gridDim.x;
    int bid = blockIdx.x;
    if ((nwg & 7) == 0) { int cpx = nwg >> 3; bid = (bid & 7) * cpx + (bid >> 3); }
    const int m0 = (bid % mblocks) * 128;
    const int n0 = (bid / mblocks) * 128;
    const int kOff = blockIdx.y * kLen;

    f32x4 acc[4][4];
    #pragma unroll
    for (int mi = 0; mi < 4; ++mi)
        #pragma unroll
        for (int ni = 0; ni < 4; ++ni) acc[mi][ni] = (f32x4){0.f, 0.f, 0.f, 0.f};

    for (int k0 = 0; k0 < kLen; k0 += 32) {
        int kk = kOff + k0;
        #pragma unroll
        for (int i = 0; i < 2; ++i) {
            int e = i * 256 + tid;
            int row = e >> 2;
            int cc = (((e & 3) ^ ((row >> 1) & 3)) << 3);     // swizzled source chunk
            int sbase = (i * 256 + (tid & ~63)) * 8;
            size_t offA = (size_t)(m0 + row) * lda + kk + cc;
            size_t offB = (size_t)(n0 + row) * lda + kk + cc;
            gload_lds16(&aH[offA], &AsH[sbase]);
            gload_lds16(&aL[offA], &AsL[sbase]);
            gload_lds16(&bH[offB], &BsH[sbase]);
            gload_lds16(&bL[offB], &BsL[sbase]);
        }
        __syncthreads();

        bf16x8 bfh[4], bfl[4];
        #pragma unroll
        for (int ni = 0; ni < 4; ++ni) {
            int row = wc * 64 + ni * 16 + lr;
            int boff = row * 32 + (lk ^ ((row >> 1) & 3)) * 8;
            bfh[ni] = *(const bf16x8*)&BsH[boff];
            bfl[ni] = *(const bf16x8*)&BsL[boff];
        }
        #pragma unroll
        for (int mi = 0; mi < 4; ++mi) {
            int row = wr * 64 + mi * 16 + lr;
            int aoff = row * 32 + (lk ^ ((row >> 1) & 3)) * 8;
            bf16x8 ah = *(const bf16x8*)&AsH[aoff];
            bf16x8 al = *(const bf16x8*)&AsL[aoff];
            #pragma unroll
            for (int ni = 0; ni < 4; ++ni) {
                acc[mi][ni] = __builtin_amdgcn_mfma_f32_16x16x32_bf16(ah, bfh[ni], acc[mi][ni], 0, 0, 0);
                acc[mi][ni] = __builtin_amdgcn_mfma_f32_16x16x32_bf16(ah, bfl[ni], acc[mi][ni], 0, 0, 0);
                acc[mi][ni] = __builtin_amdgcn_mfma_f32_16x16x32_bf16(al, bfh[ni], acc[mi][ni], 0, 0, 0);
            }
        }
        __syncthreads();
    }

    float* Cp = C;
    if (EPI == 3) Cp = C + (size_t)blockIdx.y * M * ldc;

    #pragma unroll
    for (int mi = 0; mi < 4; ++mi)
        #pragma unroll
        for (int ni = 0; ni < 4; ++ni) {
            int col  = n0 + wc * 64 + ni * 16 + lr;
            int rowb = m0 + wr * 64 + mi * 16 + lk * 4;
            #pragma unroll
            for (int j = 0; j < 4; ++j) {
                float v = acc[mi][ni][j];
                int row = rowb + j;
                if (EPI == 1) v = softplusf(v + bias[col]);
                Cp[(size_t)row * ldc + col] = v;
            }
        }
}

// ---------------- x_proj split-K reduce ----------------
__global__ __launch_bounds__(256) void xproj_reduce(
    const float* __restrict__ part, float* __restrict__ dblP,
    short* __restrict__ dtlH, short* __restrict__ dtlL)
{
    int idx = blockIdx.x * 256 + threadIdx.x;
    if (idx >= MROWS * 128) return;
    int col = idx & 127, row = idx >> 7;
    const size_t S = (size_t)MROWS * 128;
    float s = part[idx] + part[idx + S] + part[idx + 2 * S] + part[idx + 3 * S];
    if (col < 96) dblP[(size_t)row * 96 + col] = s;
    if (col < 64) {
        short h, lo; splitbf(s, h, lo);
        dtlH[(size_t)row * 64 + col] = h;
        dtlL[(size_t)row * 64 + col] = lo;
    }
}

// ---------------- Depthwise causal conv (DC=4) + SiLU, output split hi/lo ----------------
__global__ __launch_bounds__(256) void conv_silu_split(
    const float* __restrict__ xz, const float* __restrict__ cw,
    const float* __restrict__ cb, ushort* __restrict__ xcH, ushort* __restrict__ xcL)
{
    int t = blockIdx.x * 256 + threadIdx.x;
    if (t >= B_ * L_ * DI_ / 4) return;
    int d4 = (t & (DI_ / 4 - 1)) * 4;
    int ll = (t >> 9) & (L_ - 1);
    int b  = t >> 20;

    float4 w0 = *(const float4*)&cw[(d4 + 0) * 4];
    float4 w1 = *(const float4*)&cw[(d4 + 1) * 4];
    float4 w2 = *(const float4*)&cw[(d4 + 2) * 4];
    float4 w3 = *(const float4*)&cw[(d4 + 3) * 4];
    float4 bb = *(const float4*)&cb[d4];
    float a0 = bb.x, a1 = bb.y, a2 = bb.z, a3 = bb.w;

    size_t rb = (size_t)(b * L_) * 4096 + d4;
    if (ll >= 3) { float4 x = *(const float4*)&xz[rb + (size_t)(ll - 3) * 4096];
                   a0 += x.x * w0.x; a1 += x.y * w1.x; a2 += x.z * w2.x; a3 += x.w * w3.x; }
    if (ll >= 2) { float4 x = *(const float4*)&xz[rb + (size_t)(ll - 2) * 4096];
                   a0 += x.x * w0.y; a1 += x.y * w1.y; a2 += x.z * w2.y; a3 += x.w * w3.y; }
    if (ll >= 1) { float4 x = *(const float4*)&xz[rb + (size_t)(ll - 1) * 4096];
                   a0 += x.x * w0.z; a1 += x.y * w1.z; a2 += x.z * w2.z; a3 += x.w * w3.z; }
    {            float4 x = *(const float4*)&xz[rb + (size_t)ll * 4096];
                   a0 += x.x * w0.w; a1 += x.y * w1.w; a2 += x.z * w2.w; a3 += x.w * w3.w; }

    a0 *= 1.f / (1.f + __expf(-a0));
    a1 *= 1.f / (1.f + __expf(-a1));
    a2 *= 1.f / (1.f + __expf(-a2));
    a3 *= 1.f / (1.f + __expf(-a3));

    short4 hi, lo;
    splitbf(a0, hi.x, lo.x); splitbf(a1, hi.y, lo.y);
    splitbf(a2, hi.z, lo.z); splitbf(a3, hi.w, lo.w);
    size_t oidx = (size_t)(b * L_ + ll) * DI_ + d4;
    *(short4*)&xcH[oidx] = hi;
    *(short4*)&xcL[oidx] = lo;
}

// ---------------- Chunked selective scan ----------------
__global__ __launch_bounds__(256) void scan_passA(
    const float* __restrict__ xz, const ushort* __restrict__ xcH, const ushort* __restrict__ xcL,
    const float* __restrict__ dbl, const float* __restrict__ A_log,
    float* __restrict__ hbuf, float* __restrict__ pbuf, int NC)
{
    __shared__ float sB[128][16];
    const int CL = L_ / NC;
    const int d = blockIdx.x * 256 + threadIdx.x;
    const int c = blockIdx.y, b = blockIdx.z;
    const int row0 = b * L_ + c * CL;

    for (int e = threadIdx.x; e < CL * 16; e += 256) {
        int tt = e >> 4, n = e & 15;
        sB[tt][n] = dbl[(size_t)(row0 + tt) * 96 + 64 + n];
    }
    __syncthreads();

    float A[16], h[16];
    #pragma unroll
    for (int i = 0; i < 16; ++i) { A[i] = -__expf(A_log[d * 16 + i]); h[i] = 0.f; }
    float sumdt = 0.f;

    for (int tt = 0; tt < CL; ++tt) {
        size_t base = (size_t)(row0 + tt);
        float dtv = xz[base * 4096 + d];
        float xv  = bfh2f(xcH[base * 2048 + d]) + bfh2f(xcL[base * 2048 + d]);
        float dtx = dtv * xv;
        sumdt += dtv;
        #pragma unroll
        for (int i = 0; i < 16; ++i) {
            float dA = __expf(dtv * A[i]);
            h[i] = h[i] * dA + dtx * sB[tt][i];
        }
    }

    size_t sidx = (((size_t)b * NC + c) * DI_ + d) * 16;
    #pragma unroll
    for (int i = 0; i < 16; i += 4) {
        *(float4*)&hbuf[sidx + i] = make_float4(h[i], h[i+1], h[i+2], h[i+3]);
        *(float4*)&pbuf[sidx + i] = make_float4(__expf(A[i]   * sumdt), __expf(A[i+1] * sumdt),
                                                __expf(A[i+2] * sumdt), __expf(A[i+3] * sumdt));
    }
}

__global__ __launch_bounds__(256) void scan_combine(
    float* __restrict__ hbuf, const float* __restrict__ pbuf, int NC)
{
    int g = blockIdx.x * 256 + threadIdx.x;
    int n = g & 15;
    int d = (g >> 4) & (DI_ - 1);
    int b = g >> 15;
    float hin = 0.f;
    for (int c = 0; c < NC; ++c) {
        size_t idx = (((size_t)b * NC + c) * DI_ + d) * 16 + n;
        float ho = hbuf[idx], p = pbuf[idx];
        hbuf[idx] = hin;
        hin = ho + p * hin;
    }
}

__global__ __launch_bounds__(256) void scan_passC(
    ushort* __restrict__ xcH, ushort* __restrict__ xcL, const float* __restrict__ xz,
    const float* __restrict__ dbl, const float* __restrict__ A_log,
    const float* __restrict__ hbuf, const float* __restrict__ Dp, int NC)
{
    __shared__ float sBC[128][32];
    const int CL = L_ / NC;
    const int d = blockIdx.x * 256 + threadIdx.x;
    const int c = blockIdx.y, b = blockIdx.z;
    const int row0 = b * L_ + c * CL;

    for (int e = threadIdx.x; e < CL * 32; e += 256) {
        int tt = e >> 5, k = e & 31;
        sBC[tt][k] = dbl[(size_t)(row0 + tt) * 96 + 64 + k];
    }
    __syncthreads();

    float A[16], h[16];
    size_t sidx = (((size_t)b * NC + c) * DI_ + d) * 16;
    #pragma unroll
    for (int i = 0; i < 16; i += 4) {
        float4 v = *(const float4*)&hbuf[sidx + i];
        h[i] = v.x; h[i+1] = v.y; h[i+2] = v.z; h[i+3] = v.w;
    }
    #pragma unroll
    for (int i = 0; i < 16; ++i) A[i] = -__expf(A_log[d * 16 + i]);
    const float Dd = Dp[d];

    for (int tt = 0; tt < CL; ++tt) {
        size_t base = (size_t)(row0 + tt);
        float dtv = xz[base * 4096 + d];
        float xv  = bfh2f(xcH[base * 2048 + d]) + bfh2f(xcL[base * 2048 + d]);
        float zv  = xz[base * 4096 + 2048 + d];
        float dtx = dtv * xv;
        float y = 0.f;
        #pragma unroll
        for (int i = 0; i < 16; ++i) {
            float dA = __expf(dtv * A[i]);
            h[i] = h[i] * dA + dtx * sBC[tt][i];
            y = fmaf(h[i], sBC[tt][16 + i], y);
        }
        float yt = y + xv * Dd;
        float sig = 1.f / (1.f + __expf(-zv));
        float ov = yt * (zv * sig);
        short hh, lo; splitbf(ov, hh, lo);
        xcH[base * 2048 + d] = (ushort)hh;
        xcL[base * 2048 + d] = (ushort)lo;
    }
}

// ---------------- Launch ----------------
extern "C" void kernel_launch(void* const* d_in, const int* in_sizes, int n_in,
                              void* d_out, int out_size, void* d_ws, size_t ws_size,
                              hipStream_t stream)
{
    const float* u         = (const float*)d_in[0];
    const float* in_proj_w = (const float*)d_in[1];
    const float* conv_w    = (const float*)d_in[2];
    const float* conv_b    = (const float*)d_in[3];
    const float* x_proj_w  = (const float*)d_in[4];
    const float* dt_proj_w = (const float*)d_in[5];
    const float* dt_proj_b = (const float*)d_in[6];
    const float* A_log     = (const float*)d_in[7];
    const float* Dv        = (const float*)d_in[8];
    const float* out_proj_w= (const float*)d_in[9];
    float* out = (float*)d_out;

    const size_t MB = 1024ull * 1024ull;
    char* ws = (char*)d_ws;
    // ws (195 MiB fixed): xz f32 @0 (128M) | xcH bf16 @128M (32M) | xcL @160M (32M) | dblP @192M (3M)
    float*  xz   = (float*)(ws);
    ushort* xcH  = (ushort*)(ws + 128 * MB);
    ushort* xcL  = (ushort*)(ws + 160 * MB);
    float*  dblP = (float*)(ws + 192 * MB);
    short*  uH   = (short*)(ws + 128 * MB);           // 16 MiB (dead after in_proj)
    short*  uL   = (short*)(ws + 144 * MB);           // 16 MiB
    short*  wiH  = (short*)(ws + 160 * MB);           //  8 MiB
    short*  wiL  = (short*)(ws + 168 * MB);           //  8 MiB
    short*  opH  = (short*)(ws);                      //  4 MiB (xz dead post-scan)
    short*  opL  = (short*)(ws + 4 * MB);             //  4 MiB
    size_t off_tail = 195 * MB;

    // d_out (32 MiB) scratch until final GEMM overwrites it all
    char* doc = (char*)d_out;
    float* xpart = (float*)(doc);                     // 16M (x_proj partials)
    short* xpH  = (short*)(doc + 16 * MB);
    short* xpL  = (short*)(doc + 16 * MB + 512 * 1024);
    short* dtwH = (short*)(doc + 17 * MB);
    short* dtwL = (short*)(doc + 17 * MB + 256 * 1024);
    short* dtlH = (short*)(doc + 18 * MB);
    short* dtlL = (short*)(doc + 19 * MB);

    // Scan chunking: NC=32 with state in ws tail if it fits, else NC=16 in d_out.
    int NC = 32;
    size_t stateBytes = (size_t)B_ * NC * DI_ * 16 * 4;        // 16.78 MB
    float *hbuf, *pbuf;
    if (ws_size >= off_tail + 2 * stateBytes) {
        hbuf = (float*)(ws + off_tail);
        pbuf = (float*)(ws + off_tail + stateBytes);
    } else {
        NC = 16;
        hbuf = (float*)(doc);                         // after xpart is dead
        pbuf = (float*)(doc + 8 * MB);
    }

    // 1) pack u + in_proj_w; xz = u @ in_proj_w^T  (M=8192, N=4096, K=1024) -- pipelined
    pack_hl<<<(MROWS * DM_ / 4 + 255) / 256, 256, 0, stream>>>(u, uH, uL, MROWS, MROWS, DM_);
    pack_hl<<<(4096 * DM_ / 4 + 255) / 256, 256, 0, stream>>>(in_proj_w, wiH, wiL, 4096, 4096, DM_);
    gemm_pipe<<<dim3(32 * 32), 512, 0, stream>>>(
        uH, uL, wiH, wiL, xz, /*nblocks=*/32, /*lda=*/DM_, /*NT=*/DM_ / 32, /*ldc=*/2 * DI_);

    // 2) conv + silu -> xcH/xcL (split)
    conv_silu_split<<<(B_ * L_ * DI_ / 4 + 255) / 256, 256, 0, stream>>>(
        xz, conv_w, conv_b, xcH, xcL);

    // 3) x_proj: split-K=4 partials -> reduce (writes dblP + dt-input split)
    pack_hl<<<(128 * DI_ / 4 + 255) / 256, 256, 0, stream>>>(x_proj_w, xpH, xpL, 96, 128, DI_);
    gemm3<3><<<dim3(64, 4), 256, 0, stream>>>(
        (const short*)xcH, (const short*)xcL, xpH, xpL, nullptr, xpart, 64, DI_, DI_ / 4, 128, MROWS);
    xproj_reduce<<<(MROWS * 128) / 256, 256, 0, stream>>>(xpart, dblP, dtlH, dtlL);

    // 4) dt = softplus(dtl @ dt_proj_w^T + b) -> x-half of xz (ldc=4096)
    pack_hl<<<(DI_ * DR_ / 4 + 255) / 256, 256, 0, stream>>>(dt_proj_w, dtwH, dtwL, DI_, DI_, DR_);
    gemm3<1><<<dim3(1024, 1), 256, 0, stream>>>(
        dtlH, dtlL, dtwH, dtwL, dt_proj_b, xz, 64, DR_, DR_, 2 * DI_, MROWS);

    // 5) chunked scan; y (gated) written back into xcH/xcL as hi/lo
    scan_passA<<<dim3(DI_ / 256, NC, B_), 256, 0, stream>>>(xz, xcH, xcL, dblP, A_log, hbuf, pbuf, NC);
    scan_combine<<<(B_ * DI_ * 16) / 256, 256, 0, stream>>>(hbuf, pbuf, NC);
    scan_passC<<<dim3(DI_ / 256, NC, B_), 256, 0, stream>>>(xcH, xcL, xz, dblP, A_log, hbuf, Dv, NC);

    // 6) out = y @ out_proj_w^T  (M=8192, N=1024, K=2048) -- pipelined
    pack_hl<<<(DM_ * DI_ / 4 + 255) / 256, 256, 0, stream>>>(out_proj_w, opH, opL, DM_, DM_, DI_);
    gemm_pipe<<<dim3(32 * 8), 512, 0, stream>>>(
        (const short*)xcH, (const short*)xcL, opH, opL, out, /*nblocks=*/8, /*lda=*/DI_, /*NT=*/DI_ / 32, /*ldc=*/DM_);
}

// Round 14
// 592.745 us; speedup vs baseline: 1.0847x; 1.0847x over previous
//
#include <hip/hip_runtime.h>
#include <hip/hip_bf16.h>
#include <math.h>

// Problem constants
#define B_   4
#define L_   2048
#define DM_  1024
#define DS_  16
#define DI_  2048          // EXP * DM
#define DR_  64            // (DM+15)//16
#define MROWS (B_ * L_)    // 8192

typedef __attribute__((ext_vector_type(8))) short bf16x8;
typedef __attribute__((ext_vector_type(4))) float f32x4;

__device__ inline float softplusf(float x) {
    return (x > 20.f) ? x : log1pf(expf(x));
}

// ---------------- split fp32 -> bf16 hi/lo (x ~= hi + lo, rel err ~2^-17) ----------------
__device__ inline void splitbf(float x, short& h, short& l) {
    unsigned u = __builtin_bit_cast(unsigned, x);
    unsigned r = (u + 0x7FFFu + ((u >> 16) & 1u)) & 0xFFFF0000u;
    h = (short)(r >> 16);
    float lf = x - __builtin_bit_cast(float, r);
    unsigned u2 = __builtin_bit_cast(unsigned, lf);
    unsigned r2 = u2 + 0x7FFFu + ((u2 >> 16) & 1u);
    l = (short)(r2 >> 16);
}

__device__ inline float bfh2f(unsigned hs) {
    return __builtin_bit_cast(float, hs << 16);
}

// X:[R][Kin] f32 -> H,L:[Ralloc][Kin] bf16, rows >= R zeroed
__global__ __launch_bounds__(256) void pack_hl(
    const float* __restrict__ X, short* __restrict__ H, short* __restrict__ L,
    int R, int Ralloc, int Kin)
{
    int idx = blockIdx.x * 256 + threadIdx.x;       // over Ralloc*Kin/4
    int kq = Kin >> 2;
    if (idx >= Ralloc * kq) return;
    int k4 = (idx % kq) * 4, r = idx / kq;
    short4 hi = make_short4(0,0,0,0), lo = make_short4(0,0,0,0);
    if (r < R) {
        float4 v = *(const float4*)&X[(size_t)r * Kin + k4];
        splitbf(v.x, hi.x, lo.x); splitbf(v.y, hi.y, lo.y);
        splitbf(v.z, hi.z, lo.z); splitbf(v.w, hi.w, lo.w);
    }
    size_t base = (size_t)r * Kin + k4;
    *(short4*)&H[base] = hi;
    *(short4*)&L[base] = lo;
}

__device__ inline void gload_lds16(const void* g, void* s) {
    __builtin_amdgcn_global_load_lds(
        (const __attribute__((address_space(1))) void*)g,
        (__attribute__((address_space(3))) void*)s, 16, 0, 0);
}

// ================= Pipelined MFMA split-bf16 GEMM (in_proj / out_proj) =================
// C[MxN] = A*B^T with A split (aH+aL), B pure bf16 (bH): 2 products per frag.
// BM=256 BN=128 BK=32, 8 waves 4M x 2N (wave tile 64x64). Triple-buffered LDS
// (3 x 40KB = 120KB), 2-ahead prefetch, counted vmcnt(5). Swizzle per rule #21:
// linear LDS dest + pre-swizzled GLOBAL source + swizzled read (conflicts = 0, R11).
// LDS buf layout (shorts): Ah[0,8192) Al[8192,16384) Bh[16384,20480). Stride 20480.
#define BUFS 20480
__device__ inline void stage_tile(
    const short* __restrict__ aH, const short* __restrict__ aL,
    const short* __restrict__ bH,
    short* buf, int m0, int n0, int k0, int lda, int tid)
{
    int c0 = tid, c1 = tid + 512;
    int r0 = c0 >> 2, r1 = c1 >> 2;
    int p0 = (((c0 & 3) ^ ((r0 >> 1) & 3)) << 3);   // swizzled source chunk offset
    int p1 = (((c1 & 3) ^ ((r1 >> 1) & 3)) << 3);
    int ub0 = (tid & ~63) * 8;                      // wave-uniform LDS short-offset
    int ub1 = ((tid & ~63) + 512) * 8;
    gload_lds16(&aH[(size_t)(m0 + r0) * lda + k0 + p0], buf + ub0);
    gload_lds16(&aH[(size_t)(m0 + r1) * lda + k0 + p1], buf + ub1);
    gload_lds16(&aL[(size_t)(m0 + r0) * lda + k0 + p0], buf + 8192 + ub0);
    gload_lds16(&aL[(size_t)(m0 + r1) * lda + k0 + p1], buf + 8192 + ub1);
    gload_lds16(&bH[(size_t)(n0 + r0) * lda + k0 + p0], buf + 16384 + ub0);
}

__device__ __forceinline__ void read_frags(
    const short* buf, int wm, int wn, int lr, int hk,
    bf16x8 (&Ah)[4], bf16x8 (&Al)[4], bf16x8 (&Bh)[4])
{
    #pragma unroll
    for (int ni = 0; ni < 4; ++ni) {
        int row = wn * 64 + ni * 16 + lr;
        int off = 16384 + row * 32 + (hk ^ ((row >> 1) & 3)) * 8;
        Bh[ni] = *(const bf16x8*)&buf[off];
    }
    #pragma unroll
    for (int mi = 0; mi < 4; ++mi) {
        int row = wm * 64 + mi * 16 + lr;
        int off = row * 32 + (hk ^ ((row >> 1) & 3)) * 8;
        Ah[mi] = *(const bf16x8*)&buf[off];
        Al[mi] = *(const bf16x8*)&buf[off + 8192];
    }
}

__device__ __forceinline__ void tile_body(
    int t, int NT, short* lds,
    const short* __restrict__ aH, const short* __restrict__ aL,
    const short* __restrict__ bH,
    int m0, int n0, int lda, int tid, int wm, int wn, int lr, int hk,
    bf16x8 (&CAh)[4], bf16x8 (&CAl)[4], bf16x8 (&CBh)[4],
    bf16x8 (&NAh)[4], bf16x8 (&NAl)[4], bf16x8 (&NBh)[4],
    f32x4 (&acc)[4][4])
{
    // 1) stage tile t+2 into buf[(t+2)%3] (== buf[(t-1)%3], last read in tile t-2)
    if (t + 2 < NT)
        stage_tile(aH, aL, bH, &lds[((t + 2) % 3) * BUFS],
                   m0, n0, (t + 2) * 32, lda, tid);
    // 2) boundary: drain t+1's 5 stage loads (leave t+2's 5 in flight); barrier
    if (t + 1 < NT) {
        if (t + 2 < NT) asm volatile("s_waitcnt vmcnt(5)\ns_barrier" ::: "memory");
        else            asm volatile("s_waitcnt vmcnt(0)\ns_barrier" ::: "memory");
        // 3) ds_read tile t+1 frags into the NEXT register bank
        read_frags(&lds[((t + 1) % 3) * BUFS], wm, wn, lr, hk, NAh, NAl, NBh);
    }
    __builtin_amdgcn_sched_barrier(0);
    // 4) MFMA on CURRENT bank: (aH+aL) * bH -> 2 products, 32 MFMA/tile
    __builtin_amdgcn_s_setprio(1);
    #pragma unroll
    for (int mi = 0; mi < 4; ++mi)
        #pragma unroll
        for (int ni = 0; ni < 4; ++ni) {
            acc[mi][ni] = __builtin_amdgcn_mfma_f32_16x16x32_bf16(CAh[mi], CBh[ni], acc[mi][ni], 0, 0, 0);
            acc[mi][ni] = __builtin_amdgcn_mfma_f32_16x16x32_bf16(CAl[mi], CBh[ni], acc[mi][ni], 0, 0, 0);
        }
    __builtin_amdgcn_s_setprio(0);
}

__global__ __launch_bounds__(512, 2) void gemm_pipe(
    const short* __restrict__ aH, const short* __restrict__ aL,
    const short* __restrict__ bH,
    float* __restrict__ C, int nblocks, int lda, int NT, int ldc)
{
    __shared__ short lds[3 * BUFS];
    const int tid = threadIdx.x;
    const int l = tid & 63;
    const int w = tid >> 6;
    const int wm = w & 3;            // 0..3 (M quarter: 64 rows)
    const int wn = w >> 2;           // 0..1 (N half: 64 cols)
    const int lr = l & 15, hk = l >> 4;

    int nwg = gridDim.x;
    int bid = blockIdx.x;
    if ((nwg & 7) == 0) { int cpx = nwg >> 3; bid = (bid & 7) * cpx + (bid >> 3); }
    const int n0 = (bid % nblocks) * 128;
    const int m0 = (bid / nblocks) * 256;

    f32x4 acc[4][4];
    #pragma unroll
    for (int mi = 0; mi < 4; ++mi)
        #pragma unroll
        for (int ni = 0; ni < 4; ++ni) acc[mi][ni] = (f32x4){0.f, 0.f, 0.f, 0.f};

    bf16x8 A0h[4], A0l[4], B0h[4];   // register bank 0
    bf16x8 A1h[4], A1l[4], B1h[4];   // register bank 1

    // prologue: stage tiles 0,1; wait t0 (leave t1's 5); read t0 frags -> bank 0
    stage_tile(aH, aL, bH, &lds[0],    m0, n0, 0,  lda, tid);
    stage_tile(aH, aL, bH, &lds[BUFS], m0, n0, 32, lda, tid);
    asm volatile("s_waitcnt vmcnt(5)\ns_barrier" ::: "memory");
    read_frags(&lds[0], wm, wn, lr, hk, A0h, A0l, B0h);

    // NT is even (32 or 64): 2x-unrolled loop with named banks (rule #20)
    for (int t = 0; t < NT; t += 2) {
        tile_body(t,     NT, lds, aH, aL, bH, m0, n0, lda, tid, wm, wn, lr, hk,
                  A0h, A0l, B0h, A1h, A1l, B1h, acc);
        tile_body(t + 1, NT, lds, aH, aL, bH, m0, n0, lda, tid, wm, wn, lr, hk,
                  A1h, A1l, B1h, A0h, A0l, B0h, acc);
    }

    #pragma unroll
    for (int mi = 0; mi < 4; ++mi)
        #pragma unroll
        for (int ni = 0; ni < 4; ++ni) {
            int col = n0 + wn * 64 + ni * 16 + lr;
            int rowb = m0 + wm * 64 + mi * 16 + hk * 4;
            #pragma unroll
            for (int j = 0; j < 4; ++j)
                C[(size_t)(rowb + j) * ldc + col] = acc[mi][ni][j];
        }
}

// ================= 3-product fused GEMM (x_proj split-K and dt -- precision-critical) ====
template<int EPI>
__global__ __launch_bounds__(256) void gemm3(
    const short* __restrict__ aH, const short* __restrict__ aL,
    const short* __restrict__ bH, const short* __restrict__ bL,
    const float* __restrict__ bias, float* __restrict__ C,
    int mblocks, int lda, int kLen, int ldc, int M)
{
    __shared__ short AsH[128 * 32];
    __shared__ short AsL[128 * 32];
    __shared__ short BsH[128 * 32];
    __shared__ short BsL[128 * 32];

    const int tid = threadIdx.x;
    const int l  = tid & 63;
    const int wr = (tid >> 6) >> 1, wc = (tid >> 6) & 1;
    const int lr = l & 15, lk = l >> 4;

    int nwg = gridDim.x;
    int bid = blockIdx.x;
    if ((nwg & 7) == 0) { int cpx = nwg >> 3; bid = (bid & 7) * cpx + (bid >> 3); }
    const int m0 = (bid % mblocks) * 128;
    const int n0 = (bid / mblocks) * 128;
    const int kOff = blockIdx.y * kLen;

    f32x4 acc[4][4];
    #pragma unroll
    for (int mi = 0; mi < 4; ++mi)
        #pragma unroll
        for (int ni = 0; ni < 4; ++ni) acc[mi][ni] = (f32x4){0.f, 0.f, 0.f, 0.f};

    for (int k0 = 0; k0 < kLen; k0 += 32) {
        int kk = kOff + k0;
        #pragma unroll
        for (int i = 0; i < 2; ++i) {
            int e = i * 256 + tid;
            int row = e >> 2;
            int cc = (((e & 3) ^ ((row >> 1) & 3)) << 3);     // swizzled source chunk
            int sbase = (i * 256 + (tid & ~63)) * 8;
            size_t offA = (size_t)(m0 + row) * lda + kk + cc;
            size_t offB = (size_t)(n0 + row) * lda + kk + cc;
            gload_lds16(&aH[offA], &AsH[sbase]);
            gload_lds16(&aL[offA], &AsL[sbase]);
            gload_lds16(&bH[offB], &BsH[sbase]);
            gload_lds16(&bL[offB], &BsL[sbase]);
        }
        __syncthreads();

        bf16x8 bfh[4], bfl[4];
        #pragma unroll
        for (int ni = 0; ni < 4; ++ni) {
            int row = wc * 64 + ni * 16 + lr;
            int boff = row * 32 + (lk ^ ((row >> 1) & 3)) * 8;
            bfh[ni] = *(const bf16x8*)&BsH[boff];
            bfl[ni] = *(const bf16x8*)&BsL[boff];
        }
        #pragma unroll
        for (int mi = 0; mi < 4; ++mi) {
            int row = wr * 64 + mi * 16 + lr;
            int aoff = row * 32 + (lk ^ ((row >> 1) & 3)) * 8;
            bf16x8 ah = *(const bf16x8*)&AsH[aoff];
            bf16x8 al = *(const bf16x8*)&AsL[aoff];
            #pragma unroll
            for (int ni = 0; ni < 4; ++ni) {
                acc[mi][ni] = __builtin_amdgcn_mfma_f32_16x16x32_bf16(ah, bfh[ni], acc[mi][ni], 0, 0, 0);
                acc[mi][ni] = __builtin_amdgcn_mfma_f32_16x16x32_bf16(ah, bfl[ni], acc[mi][ni], 0, 0, 0);
                acc[mi][ni] = __builtin_amdgcn_mfma_f32_16x16x32_bf16(al, bfh[ni], acc[mi][ni], 0, 0, 0);
            }
        }
        __syncthreads();
    }

    float* Cp = C;
    if (EPI == 3) Cp = C + (size_t)blockIdx.y * M * ldc;

    #pragma unroll
    for (int mi = 0; mi < 4; ++mi)
        #pragma unroll
        for (int ni = 0; ni < 4; ++ni) {
            int col  = n0 + wc * 64 + ni * 16 + lr;
            int rowb = m0 + wr * 64 + mi * 16 + lk * 4;
            #pragma unroll
            for (int j = 0; j < 4; ++j) {
                float v = acc[mi][ni][j];
                int row = rowb + j;
                if (EPI == 1) v = softplusf(v + bias[col]);
                Cp[(size_t)row * ldc + col] = v;
            }
        }
}

// ---------------- x_proj split-K reduce ----------------
__global__ __launch_bounds__(256) void xproj_reduce(
    const float* __restrict__ part, float* __restrict__ dblP,
    short* __restrict__ dtlH, short* __restrict__ dtlL)
{
    int idx = blockIdx.x * 256 + threadIdx.x;
    if (idx >= MROWS * 128) return;
    int col = idx & 127, row = idx >> 7;
    const size_t S = (size_t)MROWS * 128;
    float s = part[idx] + part[idx + S] + part[idx + 2 * S] + part[idx + 3 * S];
    if (col < 96) dblP[(size_t)row * 96 + col] = s;
    if (col < 64) {
        short h, lo; splitbf(s, h, lo);
        dtlH[(size_t)row * 64 + col] = h;
        dtlL[(size_t)row * 64 + col] = lo;
    }
}

// ---------------- Depthwise causal conv (DC=4) + SiLU, output split hi/lo ----------------
__global__ __launch_bounds__(256) void conv_silu_split(
    const float* __restrict__ xz, const float* __restrict__ cw,
    const float* __restrict__ cb, ushort* __restrict__ xcH, ushort* __restrict__ xcL)
{
    int t = blockIdx.x * 256 + threadIdx.x;
    if (t >= B_ * L_ * DI_ / 4) return;
    int d4 = (t & (DI_ / 4 - 1)) * 4;
    int ll = (t >> 9) & (L_ - 1);
    int b  = t >> 20;

    float4 w0 = *(const float4*)&cw[(d4 + 0) * 4];
    float4 w1 = *(const float4*)&cw[(d4 + 1) * 4];
    float4 w2 = *(const float4*)&cw[(d4 + 2) * 4];
    float4 w3 = *(const float4*)&cw[(d4 + 3) * 4];
    float4 bb = *(const float4*)&cb[d4];
    float a0 = bb.x, a1 = bb.y, a2 = bb.z, a3 = bb.w;

    size_t rb = (size_t)(b * L_) * 4096 + d4;
    if (ll >= 3) { float4 x = *(const float4*)&xz[rb + (size_t)(ll - 3) * 4096];
                   a0 += x.x * w0.x; a1 += x.y * w1.x; a2 += x.z * w2.x; a3 += x.w * w3.x; }
    if (ll >= 2) { float4 x = *(const float4*)&xz[rb + (size_t)(ll - 2) * 4096];
                   a0 += x.x * w0.y; a1 += x.y * w1.y; a2 += x.z * w2.y; a3 += x.w * w3.y; }
    if (ll >= 1) { float4 x = *(const float4*)&xz[rb + (size_t)(ll - 1) * 4096];
                   a0 += x.x * w0.z; a1 += x.y * w1.z; a2 += x.z * w2.z; a3 += x.w * w3.z; }
    {            float4 x = *(const float4*)&xz[rb + (size_t)ll * 4096];
                   a0 += x.x * w0.w; a1 += x.y * w1.w; a2 += x.z * w2.w; a3 += x.w * w3.w; }

    a0 *= 1.f / (1.f + __expf(-a0));
    a1 *= 1.f / (1.f + __expf(-a1));
    a2 *= 1.f / (1.f + __expf(-a2));
    a3 *= 1.f / (1.f + __expf(-a3));

    short4 hi, lo;
    splitbf(a0, hi.x, lo.x); splitbf(a1, hi.y, lo.y);
    splitbf(a2, hi.z, lo.z); splitbf(a3, hi.w, lo.w);
    size_t oidx = (size_t)(b * L_ + ll) * DI_ + d4;
    *(short4*)&xcH[oidx] = hi;
    *(short4*)&xcL[oidx] = lo;
}

// ---------------- Chunked selective scan ----------------
__global__ __launch_bounds__(256) void scan_passA(
    const float* __restrict__ xz, const ushort* __restrict__ xcH, const ushort* __restrict__ xcL,
    const float* __restrict__ dbl, const float* __restrict__ A_log,
    float* __restrict__ hbuf, float* __restrict__ pbuf, int NC)
{
    __shared__ float sB[128][16];
    const int CL = L_ / NC;
    const int d = blockIdx.x * 256 + threadIdx.x;
    const int c = blockIdx.y, b = blockIdx.z;
    const int row0 = b * L_ + c * CL;

    for (int e = threadIdx.x; e < CL * 16; e += 256) {
        int tt = e >> 4, n = e & 15;
        sB[tt][n] = dbl[(size_t)(row0 + tt) * 96 + 64 + n];
    }
    __syncthreads();

    float A[16], h[16];
    #pragma unroll
    for (int i = 0; i < 16; ++i) { A[i] = -__expf(A_log[d * 16 + i]); h[i] = 0.f; }
    float sumdt = 0.f;

    for (int tt = 0; tt < CL; ++tt) {
        size_t base = (size_t)(row0 + tt);
        float dtv = xz[base * 4096 + d];
        float xv  = bfh2f(xcH[base * 2048 + d]) + bfh2f(xcL[base * 2048 + d]);
        float dtx = dtv * xv;
        sumdt += dtv;
        #pragma unroll
        for (int i = 0; i < 16; ++i) {
            float dA = __expf(dtv * A[i]);
            h[i] = h[i] * dA + dtx * sB[tt][i];
        }
    }

    size_t sidx = (((size_t)b * NC + c) * DI_ + d) * 16;
    #pragma unroll
    for (int i = 0; i < 16; i += 4) {
        *(float4*)&hbuf[sidx + i] = make_float4(h[i], h[i+1], h[i+2], h[i+3]);
        *(float4*)&pbuf[sidx + i] = make_float4(__expf(A[i]   * sumdt), __expf(A[i+1] * sumdt),
                                                __expf(A[i+2] * sumdt), __expf(A[i+3] * sumdt));
    }
}

__global__ __launch_bounds__(256) void scan_combine(
    float* __restrict__ hbuf, const float* __restrict__ pbuf, int NC)
{
    int g = blockIdx.x * 256 + threadIdx.x;
    int n = g & 15;
    int d = (g >> 4) & (DI_ - 1);
    int b = g >> 15;
    float hin = 0.f;
    for (int c = 0; c < NC; ++c) {
        size_t idx = (((size_t)b * NC + c) * DI_ + d) * 16 + n;
        float ho = hbuf[idx], p = pbuf[idx];
        hbuf[idx] = hin;
        hin = ho + p * hin;
    }
}

__global__ __launch_bounds__(256) void scan_passC(
    ushort* __restrict__ xcH, ushort* __restrict__ xcL, const float* __restrict__ xz,
    const float* __restrict__ dbl, const float* __restrict__ A_log,
    const float* __restrict__ hbuf, const float* __restrict__ Dp, int NC)
{
    __shared__ float sBC[128][32];
    const int CL = L_ / NC;
    const int d = blockIdx.x * 256 + threadIdx.x;
    const int c = blockIdx.y, b = blockIdx.z;
    const int row0 = b * L_ + c * CL;

    for (int e = threadIdx.x; e < CL * 32; e += 256) {
        int tt = e >> 5, k = e & 31;
        sBC[tt][k] = dbl[(size_t)(row0 + tt) * 96 + 64 + k];
    }
    __syncthreads();

    float A[16], h[16];
    size_t sidx = (((size_t)b * NC + c) * DI_ + d) * 16;
    #pragma unroll
    for (int i = 0; i < 16; i += 4) {
        float4 v = *(const float4*)&hbuf[sidx + i];
        h[i] = v.x; h[i+1] = v.y; h[i+2] = v.z; h[i+3] = v.w;
    }
    #pragma unroll
    for (int i = 0; i < 16; ++i) A[i] = -__expf(A_log[d * 16 + i]);
    const float Dd = Dp[d];

    for (int tt = 0; tt < CL; ++tt) {
        size_t base = (size_t)(row0 + tt);
        float dtv = xz[base * 4096 + d];
        float xv  = bfh2f(xcH[base * 2048 + d]) + bfh2f(xcL[base * 2048 + d]);
        float zv  = xz[base * 4096 + 2048 + d];
        float dtx = dtv * xv;
        float y = 0.f;
        #pragma unroll
        for (int i = 0; i < 16; ++i) {
            float dA = __expf(dtv * A[i]);
            h[i] = h[i] * dA + dtx * sBC[tt][i];
            y = fmaf(h[i], sBC[tt][16 + i], y);
        }
        float yt = y + xv * Dd;
        float sig = 1.f / (1.f + __expf(-zv));
        float ov = yt * (zv * sig);
        short hh, lo; splitbf(ov, hh, lo);
        xcH[base * 2048 + d] = (ushort)hh;
        xcL[base * 2048 + d] = (ushort)lo;
    }
}

// ---------------- Launch ----------------
extern "C" void kernel_launch(void* const* d_in, const int* in_sizes, int n_in,
                              void* d_out, int out_size, void* d_ws, size_t ws_size,
                              hipStream_t stream)
{
    const float* u         = (const float*)d_in[0];
    const float* in_proj_w = (const float*)d_in[1];
    const float* conv_w    = (const float*)d_in[2];
    const float* conv_b    = (const float*)d_in[3];
    const float* x_proj_w  = (const float*)d_in[4];
    const float* dt_proj_w = (const float*)d_in[5];
    const float* dt_proj_b = (const float*)d_in[6];
    const float* A_log     = (const float*)d_in[7];
    const float* Dv        = (const float*)d_in[8];
    const float* out_proj_w= (const float*)d_in[9];
    float* out = (float*)d_out;

    const size_t MB = 1024ull * 1024ull;
    char* ws = (char*)d_ws;
    // ws (195 MiB fixed): xz f32 @0 (128M) | xcH bf16 @128M (32M) | xcL @160M (32M) | dblP @192M (3M)
    float*  xz   = (float*)(ws);
    ushort* xcH  = (ushort*)(ws + 128 * MB);
    ushort* xcL  = (ushort*)(ws + 160 * MB);
    float*  dblP = (float*)(ws + 192 * MB);
    short*  uH   = (short*)(ws + 128 * MB);           // 16 MiB (dead after in_proj)
    short*  uL   = (short*)(ws + 144 * MB);           // 16 MiB
    short*  wiH  = (short*)(ws + 160 * MB);           //  8 MiB
    short*  wiL  = (short*)(ws + 168 * MB);           //  8 MiB
    short*  opH  = (short*)(ws);                      //  4 MiB (xz dead post-scan)
    short*  opL  = (short*)(ws + 4 * MB);             //  4 MiB
    size_t off_tail = 195 * MB;

    // d_out (32 MiB) scratch until final GEMM overwrites it all
    char* doc = (char*)d_out;
    float* xpart = (float*)(doc);                     // 16M (x_proj partials)
    short* xpH  = (short*)(doc + 16 * MB);
    short* xpL  = (short*)(doc + 16 * MB + 512 * 1024);
    short* dtwH = (short*)(doc + 17 * MB);
    short* dtwL = (short*)(doc + 17 * MB + 256 * 1024);
    short* dtlH = (short*)(doc + 18 * MB);
    short* dtlL = (short*)(doc + 19 * MB);

    // Scan chunking: NC=32 with state in ws tail if it fits, else NC=16 in d_out.
    int NC = 32;
    size_t stateBytes = (size_t)B_ * NC * DI_ * 16 * 4;        // 16.78 MB
    float *hbuf, *pbuf;
    if (ws_size >= off_tail + 2 * stateBytes) {
        hbuf = (float*)(ws + off_tail);
        pbuf = (float*)(ws + off_tail + stateBytes);
    } else {
        NC = 16;
        hbuf = (float*)(doc);                         // after xpart is dead
        pbuf = (float*)(doc + 8 * MB);
    }

    // 1) pack u + in_proj_w; xz = u @ in_proj_w^T  (M=8192, N=4096, K=1024)
    //    A = u split (uH+uL), B = weights bf16 (wiH only)
    pack_hl<<<(MROWS * DM_ / 4 + 255) / 256, 256, 0, stream>>>(u, uH, uL, MROWS, MROWS, DM_);
    pack_hl<<<(4096 * DM_ / 4 + 255) / 256, 256, 0, stream>>>(in_proj_w, wiH, wiL, 4096, 4096, DM_);
    gemm_pipe<<<dim3(32 * 32), 512, 0, stream>>>(
        uH, uL, wiH, xz, /*nblocks=*/32, /*lda=*/DM_, /*NT=*/DM_ / 32, /*ldc=*/2 * DI_);

    // 2) conv + silu -> xcH/xcL (split)
    conv_silu_split<<<(B_ * L_ * DI_ / 4 + 255) / 256, 256, 0, stream>>>(
        xz, conv_w, conv_b, xcH, xcL);

    // 3) x_proj: split-K=4 partials -> reduce (3-product; precision-critical dt input)
    pack_hl<<<(128 * DI_ / 4 + 255) / 256, 256, 0, stream>>>(x_proj_w, xpH, xpL, 96, 128, DI_);
    gemm3<3><<<dim3(64, 4), 256, 0, stream>>>(
        (const short*)xcH, (const short*)xcL, xpH, xpL, nullptr, xpart, 64, DI_, DI_ / 4, 128, MROWS);
    xproj_reduce<<<(MROWS * 128) / 256, 256, 0, stream>>>(xpart, dblP, dtlH, dtlL);

    // 4) dt = softplus(dtl @ dt_proj_w^T + b) -> x-half of xz (3-product)
    pack_hl<<<(DI_ * DR_ / 4 + 255) / 256, 256, 0, stream>>>(dt_proj_w, dtwH, dtwL, DI_, DI_, DR_);
    gemm3<1><<<dim3(1024, 1), 256, 0, stream>>>(
        dtlH, dtlL, dtwH, dtwL, dt_proj_b, xz, 64, DR_, DR_, 2 * DI_, MROWS);

    // 5) chunked scan; y (gated) written back into xcH/xcL as hi/lo
    scan_passA<<<dim3(DI_ / 256, NC, B_), 256, 0, stream>>>(xz, xcH, xcL, dblP, A_log, hbuf, pbuf, NC);
    scan_combine<<<(B_ * DI_ * 16) / 256, 256, 0, stream>>>(hbuf, pbuf, NC);
    scan_passC<<<dim3(DI_ / 256, NC, B_), 256, 0, stream>>>(xcH, xcL, xz, dblP, A_log, hbuf, Dv, NC);

    // 6) out = y @ out_proj_w^T  (M=8192, N=1024, K=2048)
    //    A = y split (xcH+xcL), B = weights bf16 (opH only)
    pack_hl<<<(DM_ * DI_ / 4 + 255) / 256, 256, 0, stream>>>(out_proj_w, opH, opL, DM_, DM_, DI_);
    gemm_pipe<<<dim3(32 * 8), 512, 0, stream>>>(
        (const short*)xcH, (const short*)xcL, opH, out, /*nblocks=*/8, /*lda=*/DI_, /*NT=*/DI_ / 32, /*ldc=*/DM_);
}

// Round 15
// 579.811 us; speedup vs baseline: 1.1089x; 1.0223x over previous
//
#include <hip/hip_runtime.h>
#include <hip/hip_bf16.h>
#include <math.h>

// Problem constants
#define B_   4
#define L_   2048
#define DM_  1024
#define DS_  16
#define DI_  2048          // EXP * DM
#define DR_  64            // (DM+15)//16
#define MROWS (B_ * L_)    // 8192

typedef __attribute__((ext_vector_type(8))) short bf16x8;
typedef __attribute__((ext_vector_type(4))) float f32x4;

__device__ inline float softplusf(float x) {
    return (x > 20.f) ? x : log1pf(expf(x));
}

// ---------------- split fp32 -> bf16 hi/lo (x ~= hi + lo, rel err ~2^-17) ----------------
__device__ inline void splitbf(float x, short& h, short& l) {
    unsigned u = __builtin_bit_cast(unsigned, x);
    unsigned r = (u + 0x7FFFu + ((u >> 16) & 1u)) & 0xFFFF0000u;
    h = (short)(r >> 16);
    float lf = x - __builtin_bit_cast(float, r);
    unsigned u2 = __builtin_bit_cast(unsigned, lf);
    unsigned r2 = u2 + 0x7FFFu + ((u2 >> 16) & 1u);
    l = (short)(r2 >> 16);
}

__device__ inline float bfh2f(unsigned hs) {
    return __builtin_bit_cast(float, hs << 16);
}

// X:[R][Kin] f32 -> H,L:[Ralloc][Kin] bf16, rows >= R zeroed
__global__ __launch_bounds__(256) void pack_hl(
    const float* __restrict__ X, short* __restrict__ H, short* __restrict__ L,
    int R, int Ralloc, int Kin)
{
    int idx = blockIdx.x * 256 + threadIdx.x;       // over Ralloc*Kin/4
    int kq = Kin >> 2;
    if (idx >= Ralloc * kq) return;
    int k4 = (idx % kq) * 4, r = idx / kq;
    short4 hi = make_short4(0,0,0,0), lo = make_short4(0,0,0,0);
    if (r < R) {
        float4 v = *(const float4*)&X[(size_t)r * Kin + k4];
        splitbf(v.x, hi.x, lo.x); splitbf(v.y, hi.y, lo.y);
        splitbf(v.z, hi.z, lo.z); splitbf(v.w, hi.w, lo.w);
    }
    size_t base = (size_t)r * Kin + k4;
    *(short4*)&H[base] = hi;
    *(short4*)&L[base] = lo;
}

__device__ inline void gload_lds16(const void* g, void* s) {
    __builtin_amdgcn_global_load_lds(
        (const __attribute__((address_space(1))) void*)g,
        (__attribute__((address_space(3))) void*)s, 16, 0, 0);
}

// ================= Pipelined MFMA split-bf16 GEMM (in_proj / out_proj) =================
// C[MxN] = A*B^T with A split (aH+aL), B pure bf16 (bH): 2 products per frag.
// BM=256 BN=128 BK=32, 8 waves 4M x 2N (wave tile 64x64). DOUBLE-buffered LDS
// (2 x 40KB = 80KB) -> 2 blocks/CU co-resident: one block's MFMA phase overlaps the
// other's LDS/stage phase via the CU scheduler (TLP; the m114/m97 mechanism) -- R11-R13
// showed the compiler refuses intra-wave overlap, so get it across blocks instead.
// Per tile: stage t+1 -> other buf; read frags t; 32 MFMA; vmcnt(0)+barrier (loads get
// the full read+MFMA duration ~2100cyc > 900cyc HBM latency -> drain nearly free).
// Swizzle per rule #21: linear LDS dest + pre-swizzled GLOBAL source + swizzled read
// (bank conflicts = 0, measured R11).
// LDS buf layout (shorts): Ah[0,8192) Al[8192,16384) Bh[16384,20480). Stride 20480.
#define BUFS 20480
__device__ inline void stage_tile(
    const short* __restrict__ aH, const short* __restrict__ aL,
    const short* __restrict__ bH,
    short* buf, int m0, int n0, int k0, int lda, int tid)
{
    int c0 = tid, c1 = tid + 512;
    int r0 = c0 >> 2, r1 = c1 >> 2;
    int p0 = (((c0 & 3) ^ ((r0 >> 1) & 3)) << 3);   // swizzled source chunk offset
    int p1 = (((c1 & 3) ^ ((r1 >> 1) & 3)) << 3);
    int ub0 = (tid & ~63) * 8;                      // wave-uniform LDS short-offset
    int ub1 = ((tid & ~63) + 512) * 8;
    gload_lds16(&aH[(size_t)(m0 + r0) * lda + k0 + p0], buf + ub0);
    gload_lds16(&aH[(size_t)(m0 + r1) * lda + k0 + p1], buf + ub1);
    gload_lds16(&aL[(size_t)(m0 + r0) * lda + k0 + p0], buf + 8192 + ub0);
    gload_lds16(&aL[(size_t)(m0 + r1) * lda + k0 + p1], buf + 8192 + ub1);
    gload_lds16(&bH[(size_t)(n0 + r0) * lda + k0 + p0], buf + 16384 + ub0);
}

__device__ __forceinline__ void read_frags(
    const short* buf, int wm, int wn, int lr, int hk,
    bf16x8 (&Ah)[4], bf16x8 (&Al)[4], bf16x8 (&Bh)[4])
{
    #pragma unroll
    for (int ni = 0; ni < 4; ++ni) {
        int row = wn * 64 + ni * 16 + lr;
        int off = 16384 + row * 32 + (hk ^ ((row >> 1) & 3)) * 8;
        Bh[ni] = *(const bf16x8*)&buf[off];
    }
    #pragma unroll
    for (int mi = 0; mi < 4; ++mi) {
        int row = wm * 64 + mi * 16 + lr;
        int off = row * 32 + (hk ^ ((row >> 1) & 3)) * 8;
        Ah[mi] = *(const bf16x8*)&buf[off];
        Al[mi] = *(const bf16x8*)&buf[off + 8192];
    }
}

__global__ __launch_bounds__(512, 4) void gemm_pipe(
    const short* __restrict__ aH, const short* __restrict__ aL,
    const short* __restrict__ bH,
    float* __restrict__ C, int nblocks, int lda, int NT, int ldc)
{
    __shared__ short lds[2 * BUFS];                 // 80 KB -> 2 blocks/CU
    const int tid = threadIdx.x;
    const int l = tid & 63;
    const int w = tid >> 6;
    const int wm = w & 3;            // 0..3 (M quarter: 64 rows)
    const int wn = w >> 2;           // 0..1 (N half: 64 cols)
    const int lr = l & 15, hk = l >> 4;

    int nwg = gridDim.x;
    int bid = blockIdx.x;
    if ((nwg & 7) == 0) { int cpx = nwg >> 3; bid = (bid & 7) * cpx + (bid >> 3); }
    const int n0 = (bid % nblocks) * 128;
    const int m0 = (bid / nblocks) * 256;

    f32x4 acc[4][4];
    #pragma unroll
    for (int mi = 0; mi < 4; ++mi)
        #pragma unroll
        for (int ni = 0; ni < 4; ++ni) acc[mi][ni] = (f32x4){0.f, 0.f, 0.f, 0.f};

    // prologue: stage tile 0 into buf0
    stage_tile(aH, aL, bH, &lds[0], m0, n0, 0, lda, tid);
    asm volatile("s_waitcnt vmcnt(0)\ns_barrier" ::: "memory");

    for (int t = 0; t < NT; ++t) {
        short* buf = &lds[(t & 1) * BUFS];
        // stage t+1 into the OTHER buffer (its frags were consumed in iter t-1;
        // the barrier ending iter t-1 certifies all waves are done with it)
        if (t + 1 < NT)
            stage_tile(aH, aL, bH, &lds[((t + 1) & 1) * BUFS],
                       m0, n0, (t + 1) * 32, lda, tid);

        bf16x8 Ah[4], Al[4], Bh[4];
        read_frags(buf, wm, wn, lr, hk, Ah, Al, Bh);

        __builtin_amdgcn_s_setprio(1);
        #pragma unroll
        for (int mi = 0; mi < 4; ++mi)
            #pragma unroll
            for (int ni = 0; ni < 4; ++ni) {
                acc[mi][ni] = __builtin_amdgcn_mfma_f32_16x16x32_bf16(Ah[mi], Bh[ni], acc[mi][ni], 0, 0, 0);
                acc[mi][ni] = __builtin_amdgcn_mfma_f32_16x16x32_bf16(Al[mi], Bh[ni], acc[mi][ni], 0, 0, 0);
            }
        __builtin_amdgcn_s_setprio(0);

        // t+1's loads had the whole read+MFMA span to land; drain remainder + sync
        asm volatile("s_waitcnt vmcnt(0)\ns_barrier" ::: "memory");
    }

    #pragma unroll
    for (int mi = 0; mi < 4; ++mi)
        #pragma unroll
        for (int ni = 0; ni < 4; ++ni) {
            int col = n0 + wn * 64 + ni * 16 + lr;
            int rowb = m0 + wm * 64 + mi * 16 + hk * 4;
            #pragma unroll
            for (int j = 0; j < 4; ++j)
                C[(size_t)(rowb + j) * ldc + col] = acc[mi][ni][j];
        }
}

// ================= 3-product fused GEMM (x_proj split-K and dt -- precision-critical) ====
template<int EPI>
__global__ __launch_bounds__(256) void gemm3(
    const short* __restrict__ aH, const short* __restrict__ aL,
    const short* __restrict__ bH, const short* __restrict__ bL,
    const float* __restrict__ bias, float* __restrict__ C,
    int mblocks, int lda, int kLen, int ldc, int M)
{
    __shared__ short AsH[128 * 32];
    __shared__ short AsL[128 * 32];
    __shared__ short BsH[128 * 32];
    __shared__ short BsL[128 * 32];

    const int tid = threadIdx.x;
    const int l  = tid & 63;
    const int wr = (tid >> 6) >> 1, wc = (tid >> 6) & 1;
    const int lr = l & 15, lk = l >> 4;

    int nwg = gridDim.x;
    int bid = blockIdx.x;
    if ((nwg & 7) == 0) { int cpx = nwg >> 3; bid = (bid & 7) * cpx + (bid >> 3); }
    const int m0 = (bid % mblocks) * 128;
    const int n0 = (bid / mblocks) * 128;
    const int kOff = blockIdx.y * kLen;

    f32x4 acc[4][4];
    #pragma unroll
    for (int mi = 0; mi < 4; ++mi)
        #pragma unroll
        for (int ni = 0; ni < 4; ++ni) acc[mi][ni] = (f32x4){0.f, 0.f, 0.f, 0.f};

    for (int k0 = 0; k0 < kLen; k0 += 32) {
        int kk = kOff + k0;
        #pragma unroll
        for (int i = 0; i < 2; ++i) {
            int e = i * 256 + tid;
            int row = e >> 2;
            int cc = (((e & 3) ^ ((row >> 1) & 3)) << 3);     // swizzled source chunk
            int sbase = (i * 256 + (tid & ~63)) * 8;
            size_t offA = (size_t)(m0 + row) * lda + kk + cc;
            size_t offB = (size_t)(n0 + row) * lda + kk + cc;
            gload_lds16(&aH[offA], &AsH[sbase]);
            gload_lds16(&aL[offA], &AsL[sbase]);
            gload_lds16(&bH[offB], &BsH[sbase]);
            gload_lds16(&bL[offB], &BsL[sbase]);
        }
        __syncthreads();

        bf16x8 bfh[4], bfl[4];
        #pragma unroll
        for (int ni = 0; ni < 4; ++ni) {
            int row = wc * 64 + ni * 16 + lr;
            int boff = row * 32 + (lk ^ ((row >> 1) & 3)) * 8;
            bfh[ni] = *(const bf16x8*)&BsH[boff];
            bfl[ni] = *(const bf16x8*)&BsL[boff];
        }
        #pragma unroll
        for (int mi = 0; mi < 4; ++mi) {
            int row = wr * 64 + mi * 16 + lr;
            int aoff = row * 32 + (lk ^ ((row >> 1) & 3)) * 8;
            bf16x8 ah = *(const bf16x8*)&AsH[aoff];
            bf16x8 al = *(const bf16x8*)&AsL[aoff];
            #pragma unroll
            for (int ni = 0; ni < 4; ++ni) {
                acc[mi][ni] = __builtin_amdgcn_mfma_f32_16x16x32_bf16(ah, bfh[ni], acc[mi][ni], 0, 0, 0);
                acc[mi][ni] = __builtin_amdgcn_mfma_f32_16x16x32_bf16(ah, bfl[ni], acc[mi][ni], 0, 0, 0);
                acc[mi][ni] = __builtin_amdgcn_mfma_f32_16x16x32_bf16(al, bfh[ni], acc[mi][ni], 0, 0, 0);
            }
        }
        __syncthreads();
    }

    float* Cp = C;
    if (EPI == 3) Cp = C + (size_t)blockIdx.y * M * ldc;

    #pragma unroll
    for (int mi = 0; mi < 4; ++mi)
        #pragma unroll
        for (int ni = 0; ni < 4; ++ni) {
            int col  = n0 + wc * 64 + ni * 16 + lr;
            int rowb = m0 + wr * 64 + mi * 16 + lk * 4;
            #pragma unroll
            for (int j = 0; j < 4; ++j) {
                float v = acc[mi][ni][j];
                int row = rowb + j;
                if (EPI == 1) v = softplusf(v + bias[col]);
                Cp[(size_t)row * ldc + col] = v;
            }
        }
}

// ---------------- x_proj split-K reduce ----------------
__global__ __launch_bounds__(256) void xproj_reduce(
    const float* __restrict__ part, float* __restrict__ dblP,
    short* __restrict__ dtlH, short* __restrict__ dtlL)
{
    int idx = blockIdx.x * 256 + threadIdx.x;
    if (idx >= MROWS * 128) return;
    int col = idx & 127, row = idx >> 7;
    const size_t S = (size_t)MROWS * 128;
    float s = part[idx] + part[idx + S] + part[idx + 2 * S] + part[idx + 3 * S];
    if (col < 96) dblP[(size_t)row * 96 + col] = s;
    if (col < 64) {
        short h, lo; splitbf(s, h, lo);
        dtlH[(size_t)row * 64 + col] = h;
        dtlL[(size_t)row * 64 + col] = lo;
    }
}

// ---------------- Depthwise causal conv (DC=4) + SiLU, output split hi/lo ----------------
__global__ __launch_bounds__(256) void conv_silu_split(
    const float* __restrict__ xz, const float* __restrict__ cw,
    const float* __restrict__ cb, ushort* __restrict__ xcH, ushort* __restrict__ xcL)
{
    int t = blockIdx.x * 256 + threadIdx.x;
    if (t >= B_ * L_ * DI_ / 4) return;
    int d4 = (t & (DI_ / 4 - 1)) * 4;
    int ll = (t >> 9) & (L_ - 1);
    int b  = t >> 20;

    float4 w0 = *(const float4*)&cw[(d4 + 0) * 4];
    float4 w1 = *(const float4*)&cw[(d4 + 1) * 4];
    float4 w2 = *(const float4*)&cw[(d4 + 2) * 4];
    float4 w3 = *(const float4*)&cw[(d4 + 3) * 4];
    float4 bb = *(const float4*)&cb[d4];
    float a0 = bb.x, a1 = bb.y, a2 = bb.z, a3 = bb.w;

    size_t rb = (size_t)(b * L_) * 4096 + d4;
    if (ll >= 3) { float4 x = *(const float4*)&xz[rb + (size_t)(ll - 3) * 4096];
                   a0 += x.x * w0.x; a1 += x.y * w1.x; a2 += x.z * w2.x; a3 += x.w * w3.x; }
    if (ll >= 2) { float4 x = *(const float4*)&xz[rb + (size_t)(ll - 2) * 4096];
                   a0 += x.x * w0.y; a1 += x.y * w1.y; a2 += x.z * w2.y; a3 += x.w * w3.y; }
    if (ll >= 1) { float4 x = *(const float4*)&xz[rb + (size_t)(ll - 1) * 4096];
                   a0 += x.x * w0.z; a1 += x.y * w1.z; a2 += x.z * w2.z; a3 += x.w * w3.z; }
    {            float4 x = *(const float4*)&xz[rb + (size_t)ll * 4096];
                   a0 += x.x * w0.w; a1 += x.y * w1.w; a2 += x.z * w2.w; a3 += x.w * w3.w; }

    a0 *= 1.f / (1.f + __expf(-a0));
    a1 *= 1.f / (1.f + __expf(-a1));
    a2 *= 1.f / (1.f + __expf(-a2));
    a3 *= 1.f / (1.f + __expf(-a3));

    short4 hi, lo;
    splitbf(a0, hi.x, lo.x); splitbf(a1, hi.y, lo.y);
    splitbf(a2, hi.z, lo.z); splitbf(a3, hi.w, lo.w);
    size_t oidx = (size_t)(b * L_ + ll) * DI_ + d4;
    *(short4*)&xcH[oidx] = hi;
    *(short4*)&xcL[oidx] = lo;
}

// ---------------- Chunked selective scan ----------------
__global__ __launch_bounds__(256) void scan_passA(
    const float* __restrict__ xz, const ushort* __restrict__ xcH, const ushort* __restrict__ xcL,
    const float* __restrict__ dbl, const float* __restrict__ A_log,
    float* __restrict__ hbuf, float* __restrict__ pbuf, int NC)
{
    __shared__ float sB[128][16];
    const int CL = L_ / NC;
    const int d = blockIdx.x * 256 + threadIdx.x;
    const int c = blockIdx.y, b = blockIdx.z;
    const int row0 = b * L_ + c * CL;

    for (int e = threadIdx.x; e < CL * 16; e += 256) {
        int tt = e >> 4, n = e & 15;
        sB[tt][n] = dbl[(size_t)(row0 + tt) * 96 + 64 + n];
    }
    __syncthreads();

    float A[16], h[16];
    #pragma unroll
    for (int i = 0; i < 16; ++i) { A[i] = -__expf(A_log[d * 16 + i]); h[i] = 0.f; }
    float sumdt = 0.f;

    for (int tt = 0; tt < CL; ++tt) {
        size_t base = (size_t)(row0 + tt);
        float dtv = xz[base * 4096 + d];
        float xv  = bfh2f(xcH[base * 2048 + d]) + bfh2f(xcL[base * 2048 + d]);
        float dtx = dtv * xv;
        sumdt += dtv;
        #pragma unroll
        for (int i = 0; i < 16; ++i) {
            float dA = __expf(dtv * A[i]);
            h[i] = h[i] * dA + dtx * sB[tt][i];
        }
    }

    size_t sidx = (((size_t)b * NC + c) * DI_ + d) * 16;
    #pragma unroll
    for (int i = 0; i < 16; i += 4) {
        *(float4*)&hbuf[sidx + i] = make_float4(h[i], h[i+1], h[i+2], h[i+3]);
        *(float4*)&pbuf[sidx + i] = make_float4(__expf(A[i]   * sumdt), __expf(A[i+1] * sumdt),
                                                __expf(A[i+2] * sumdt), __expf(A[i+3] * sumdt));
    }
}

__global__ __launch_bounds__(256) void scan_combine(
    float* __restrict__ hbuf, const float* __restrict__ pbuf, int NC)
{
    int g = blockIdx.x * 256 + threadIdx.x;
    int n = g & 15;
    int d = (g >> 4) & (DI_ - 1);
    int b = g >> 15;
    float hin = 0.f;
    for (int c = 0; c < NC; ++c) {
        size_t idx = (((size_t)b * NC + c) * DI_ + d) * 16 + n;
        float ho = hbuf[idx], p = pbuf[idx];
        hbuf[idx] = hin;
        hin = ho + p * hin;
    }
}

__global__ __launch_bounds__(256) void scan_passC(
    ushort* __restrict__ xcH, ushort* __restrict__ xcL, const float* __restrict__ xz,
    const float* __restrict__ dbl, const float* __restrict__ A_log,
    const float* __restrict__ hbuf, const float* __restrict__ Dp, int NC)
{
    __shared__ float sBC[128][32];
    const int CL = L_ / NC;
    const int d = blockIdx.x * 256 + threadIdx.x;
    const int c = blockIdx.y, b = blockIdx.z;
    const int row0 = b * L_ + c * CL;

    for (int e = threadIdx.x; e < CL * 32; e += 256) {
        int tt = e >> 5, k = e & 31;
        sBC[tt][k] = dbl[(size_t)(row0 + tt) * 96 + 64 + k];
    }
    __syncthreads();

    float A[16], h[16];
    size_t sidx = (((size_t)b * NC + c) * DI_ + d) * 16;
    #pragma unroll
    for (int i = 0; i < 16; i += 4) {
        float4 v = *(const float4*)&hbuf[sidx + i];
        h[i] = v.x; h[i+1] = v.y; h[i+2] = v.z; h[i+3] = v.w;
    }
    #pragma unroll
    for (int i = 0; i < 16; ++i) A[i] = -__expf(A_log[d * 16 + i]);
    const float Dd = Dp[d];

    for (int tt = 0; tt < CL; ++tt) {
        size_t base = (size_t)(row0 + tt);
        float dtv = xz[base * 4096 + d];
        float xv  = bfh2f(xcH[base * 2048 + d]) + bfh2f(xcL[base * 2048 + d]);
        float zv  = xz[base * 4096 + 2048 + d];
        float dtx = dtv * xv;
        float y = 0.f;
        #pragma unroll
        for (int i = 0; i < 16; ++i) {
            float dA = __expf(dtv * A[i]);
            h[i] = h[i] * dA + dtx * sBC[tt][i];
            y = fmaf(h[i], sBC[tt][16 + i], y);
        }
        float yt = y + xv * Dd;
        float sig = 1.f / (1.f + __expf(-zv));
        float ov = yt * (zv * sig);
        short hh, lo; splitbf(ov, hh, lo);
        xcH[base * 2048 + d] = (ushort)hh;
        xcL[base * 2048 + d] = (ushort)lo;
    }
}

// ---------------- Launch ----------------
extern "C" void kernel_launch(void* const* d_in, const int* in_sizes, int n_in,
                              void* d_out, int out_size, void* d_ws, size_t ws_size,
                              hipStream_t stream)
{
    const float* u         = (const float*)d_in[0];
    const float* in_proj_w = (const float*)d_in[1];
    const float* conv_w    = (const float*)d_in[2];
    const float* conv_b    = (const float*)d_in[3];
    const float* x_proj_w  = (const float*)d_in[4];
    const float* dt_proj_w = (const float*)d_in[5];
    const float* dt_proj_b = (const float*)d_in[6];
    const float* A_log     = (const float*)d_in[7];
    const float* Dv        = (const float*)d_in[8];
    const float* out_proj_w= (const float*)d_in[9];
    float* out = (float*)d_out;

    const size_t MB = 1024ull * 1024ull;
    char* ws = (char*)d_ws;
    // ws (195 MiB fixed): xz f32 @0 (128M) | xcH bf16 @128M (32M) | xcL @160M (32M) | dblP @192M (3M)
    float*  xz   = (float*)(ws);
    ushort* xcH  = (ushort*)(ws + 128 * MB);
    ushort* xcL  = (ushort*)(ws + 160 * MB);
    float*  dblP = (float*)(ws + 192 * MB);
    short*  uH   = (short*)(ws + 128 * MB);           // 16 MiB (dead after in_proj)
    short*  uL   = (short*)(ws + 144 * MB);           // 16 MiB
    short*  wiH  = (short*)(ws + 160 * MB);           //  8 MiB
    short*  wiL  = (short*)(ws + 168 * MB);           //  8 MiB
    short*  opH  = (short*)(ws);                      //  4 MiB (xz dead post-scan)
    short*  opL  = (short*)(ws + 4 * MB);             //  4 MiB
    size_t off_tail = 195 * MB;

    // d_out (32 MiB) scratch until final GEMM overwrites it all
    char* doc = (char*)d_out;
    float* xpart = (float*)(doc);                     // 16M (x_proj partials)
    short* xpH  = (short*)(doc + 16 * MB);
    short* xpL  = (short*)(doc + 16 * MB + 512 * 1024);
    short* dtwH = (short*)(doc + 17 * MB);
    short* dtwL = (short*)(doc + 17 * MB + 256 * 1024);
    short* dtlH = (short*)(doc + 18 * MB);
    short* dtlL = (short*)(doc + 19 * MB);

    // Scan chunking: NC=32 with state in ws tail if it fits, else NC=16 in d_out.
    int NC = 32;
    size_t stateBytes = (size_t)B_ * NC * DI_ * 16 * 4;        // 16.78 MB
    float *hbuf, *pbuf;
    if (ws_size >= off_tail + 2 * stateBytes) {
        hbuf = (float*)(ws + off_tail);
        pbuf = (float*)(ws + off_tail + stateBytes);
    } else {
        NC = 16;
        hbuf = (float*)(doc);                         // after xpart is dead
        pbuf = (float*)(doc + 8 * MB);
    }

    // 1) pack u + in_proj_w; xz = u @ in_proj_w^T  (M=8192, N=4096, K=1024)
    //    A = u split (uH+uL), B = weights bf16 (wiH only)
    pack_hl<<<(MROWS * DM_ / 4 + 255) / 256, 256, 0, stream>>>(u, uH, uL, MROWS, MROWS, DM_);
    pack_hl<<<(4096 * DM_ / 4 + 255) / 256, 256, 0, stream>>>(in_proj_w, wiH, wiL, 4096, 4096, DM_);
    gemm_pipe<<<dim3(32 * 32), 512, 0, stream>>>(
        uH, uL, wiH, xz, /*nblocks=*/32, /*lda=*/DM_, /*NT=*/DM_ / 32, /*ldc=*/2 * DI_);

    // 2) conv + silu -> xcH/xcL (split)
    conv_silu_split<<<(B_ * L_ * DI_ / 4 + 255) / 256, 256, 0, stream>>>(
        xz, conv_w, conv_b, xcH, xcL);

    // 3) x_proj: split-K=4 partials -> reduce (3-product; precision-critical dt input)
    pack_hl<<<(128 * DI_ / 4 + 255) / 256, 256, 0, stream>>>(x_proj_w, xpH, xpL, 96, 128, DI_);
    gemm3<3><<<dim3(64, 4), 256, 0, stream>>>(
        (const short*)xcH, (const short*)xcL, xpH, xpL, nullptr, xpart, 64, DI_, DI_ / 4, 128, MROWS);
    xproj_reduce<<<(MROWS * 128) / 256, 256, 0, stream>>>(xpart, dblP, dtlH, dtlL);

    // 4) dt = softplus(dtl @ dt_proj_w^T + b) -> x-half of xz (3-product)
    pack_hl<<<(DI_ * DR_ / 4 + 255) / 256, 256, 0, stream>>>(dt_proj_w, dtwH, dtwL, DI_, DI_, DR_);
    gemm3<1><<<dim3(1024, 1), 256, 0, stream>>>(
        dtlH, dtlL, dtwH, dtwL, dt_proj_b, xz, 64, DR_, DR_, 2 * DI_, MROWS);

    // 5) chunked scan; y (gated) written back into xcH/xcL as hi/lo
    scan_passA<<<dim3(DI_ / 256, NC, B_), 256, 0, stream>>>(xz, xcH, xcL, dblP, A_log, hbuf, pbuf, NC);
    scan_combine<<<(B_ * DI_ * 16) / 256, 256, 0, stream>>>(hbuf, pbuf, NC);
    scan_passC<<<dim3(DI_ / 256, NC, B_), 256, 0, stream>>>(xcH, xcL, xz, dblP, A_log, hbuf, Dv, NC);

    // 6) out = y @ out_proj_w^T  (M=8192, N=1024, K=2048)
    //    A = y split (xcH+xcL), B = weights bf16 (opH only)
    pack_hl<<<(DM_ * DI_ / 4 + 255) / 256, 256, 0, stream>>>(out_proj_w, opH, opL, DM_, DM_, DI_);
    gemm_pipe<<<dim3(32 * 8), 512, 0, stream>>>(
        (const short*)xcH, (const short*)xcL, opH, out, /*nblocks=*/8, /*lda=*/DI_, /*NT=*/DI_ / 32, /*ldc=*/DM_);
}